// Round 1
// baseline (160.333 us; speedup 1.0000x reference)
//
#include <hip/hip_runtime.h>

#define WALK_LEN 40
#define WINDOW   5
#define NPAIRS   370
#define BATCHSZ  512
#define NEGK     5
#define NPOS     (BATCHSZ * NPAIRS)   // 189440
#define NNEG     (NPOS * NEGK)        // 947200
#define NTASK    (NPOS + NNEG)        // 1136640
#define EMB      128

struct PairTab { short src[NPAIRS]; short dst[NPAIRS]; };

constexpr PairTab make_pairs() {
    PairTab t{};
    int k = 0;
    for (int i = 0; i < WALK_LEN; ++i) {
        int lo = (i - WINDOW > 0) ? (i - WINDOW) : 0;
        for (int j = lo; j < i; ++j) { t.src[k] = (short)j; t.dst[k] = (short)i; ++k; }
        int hi = (i + 1 + WINDOW < WALK_LEN) ? (i + 1 + WINDOW) : WALK_LEN;
        for (int j = i + 1; j < hi; ++j) { t.src[k] = (short)j; t.dst[k] = (short)i; ++k; }
    }
    return t;
}

__constant__ PairTab g_pairs = make_pairs();

// One task = one (src,dst) pair -> dot128 -> softplus term.
// 32 lanes per task: each lane loads one float4 from each row (512B coalesced).
__global__ __launch_bounds__(256) void deepwalk_loss_kernel(
    const int*   __restrict__ walk,     // [BATCHSZ*WALK_LEN] node ids
    const int*   __restrict__ negdst,   // [NNEG] indices into [0, BATCHSZ*WALK_LEN)
    const float* __restrict__ nodeE,    // [1e6 * 128]
    const float* __restrict__ ctxE,     // [1e6 * 128]
    float*       __restrict__ out)      // [1], pre-zeroed
{
    const int lane = threadIdx.x & 31;
    const int grp  = threadIdx.x >> 5;          // 0..7 task-groups per block
    float lsum = 0.0f;

    for (int task = blockIdx.x * 8 + grp; task < NTASK; task += gridDim.x * 8) {
        int srow, drow;
        const bool pos = (task < NPOS);
        if (pos) {
            int b = task / NPAIRS;
            int j = task - b * NPAIRS;
            srow = walk[b * WALK_LEN + g_pairs.src[j]];   // node-embed row
            drow = walk[b * WALK_LEN + g_pairs.dst[j]];   // ctx-embed row
        } else {
            int t = task - NPOS;                          // 0..NNEG-1
            int p = t / NEGK;                             // positive pair index
            int b = p / NPAIRS;
            int j = p - b * NPAIRS;
            srow = walk[b * WALK_LEN + g_pairs.dst[j]];   // neg src = batch_node[idx_dst]
            drow = walk[negdst[t]];                       // neg dst = batch_ctx[neg_idx_dst]
        }

        const float4 a = *((const float4*)(nodeE + (size_t)srow * EMB) + lane);
        const float4 c = *((const float4*)(ctxE  + (size_t)drow * EMB) + lane);
        float d = a.x * c.x + a.y * c.y + a.z * c.z + a.w * c.w;

        // reduce across the 32 lanes of this task-group (xor masks < 32 stay in-half)
        #pragma unroll
        for (int m = 1; m < 32; m <<= 1) d += __shfl_xor(d, m);

        if (lane == 0) {
            float s = fminf(6.0f, fmaxf(-6.0f, d));
            // pos term: softplus(-s); neg term: softplus(+s)
            float x = pos ? -s : s;
            lsum += log1pf(expf(x));
        }
    }

    // combine the two 32-lane halves of each wave (lane 0 and lane 32 hold partials)
    lsum += __shfl_xor(lsum, 32);

    __shared__ float wsum[4];
    if ((threadIdx.x & 63) == 0) wsum[threadIdx.x >> 6] = lsum;
    __syncthreads();
    if (threadIdx.x == 0) {
        float tot = wsum[0] + wsum[1] + wsum[2] + wsum[3];
        atomicAdd(out, tot * (1.0f / (float)NPOS));
    }
}

extern "C" void kernel_launch(void* const* d_in, const int* in_sizes, int n_in,
                              void* d_out, int out_size, void* d_ws, size_t ws_size,
                              hipStream_t stream) {
    const int*   walk   = (const int*)d_in[0];
    const int*   negdst = (const int*)d_in[1];
    const float* nodeE  = (const float*)d_in[2];
    const float* ctxE   = (const float*)d_in[3];
    float*       out    = (float*)d_out;

    hipMemsetAsync(out, 0, sizeof(float), stream);
    deepwalk_loss_kernel<<<4096, 256, 0, stream>>>(walk, negdst, nodeE, ctxE, out);
}